// Round 3
// baseline (82.175 us; speedup 1.0000x reference)
//
#include <hip/hip_runtime.h>
#include <math.h>

// N=1024, D=128, tau=1, beta=1. Single fused kernel:
//   grid (64, 2): blockIdx.x = 16-row i-tile, blockIdx.y = pair (0: x/lp, 1: x/aug)
//   block 1024 threads = 16 waves; wave w covers j in [w*64, w*64+64) as 4 16-col tiles.
//   Each block: fp32 loads straight from d_in -> bf16 frags + exact fp32 norms ->
//   MFMA dots -> d2 = nx+ny-2dot -> dm -> exp-rowsum -> pos - log(denom) ->
//   atomicAdd into d_out (poison cleared via atomicCAS 0xAAAAAAAA -> 0).
#define NN 1024
#define DD 128

typedef __bf16 bf16x8 __attribute__((ext_vector_type(8)));
typedef float  floatx4 __attribute__((ext_vector_type(4)));

__global__ __launch_bounds__(1024) void align_fused(
    const float* __restrict__ x, const float* __restrict__ lp,
    const float* __restrict__ aug, float* __restrict__ out)
{
    const float SCALE = 0.08838834764831845f;  // 1/sqrt(128)
    const int p    = blockIdx.y;
    const float* __restrict__ Y = p ? aug : lp;
    const int i0   = blockIdx.x * 16;
    const int tid  = threadIdx.x;
    const int w    = tid >> 6;    // wave 0..15
    const int lane = tid & 63;
    const int col  = lane & 15;   // A-frag row / C col
    const int quad = lane >> 4;   // 0..3

    // ---- A fragments (x row i0+col, k = c*32 + quad*8 + [0..7]) + exact norm ----
    const float* xrow = x + (size_t)(i0 + col) * DD + quad * 8;
    bf16x8 afrag[4];
    float nx_own = 0.f;
#pragma unroll
    for (int c = 0; c < 4; ++c) {
        const float4 u0 = *(const float4*)(xrow + c * 32);
        const float4 u1 = *(const float4*)(xrow + c * 32 + 4);
        nx_own += u0.x*u0.x + u0.y*u0.y + u0.z*u0.z + u0.w*u0.w;
        nx_own += u1.x*u1.x + u1.y*u1.y + u1.z*u1.z + u1.w*u1.w;
        bf16x8 f;
        f[0]=(__bf16)u0.x; f[1]=(__bf16)u0.y; f[2]=(__bf16)u0.z; f[3]=(__bf16)u0.w;
        f[4]=(__bf16)u1.x; f[5]=(__bf16)u1.y; f[6]=(__bf16)u1.z; f[7]=(__bf16)u1.w;
        afrag[c] = f;
    }
    nx_own += __shfl_xor(nx_own, 16);
    nx_own += __shfl_xor(nx_own, 32);     // full ||x_(i0+col)||^2
    float nxr[4];
#pragma unroll
    for (int r = 0; r < 4; ++r) nxr[r] = __shfl(nx_own, quad * 4 + r);

    float denom[4] = {0.f, 0.f, 0.f, 0.f};
    float pos[4]   = {0.f, 0.f, 0.f, 0.f};

#pragma unroll
    for (int t = 0; t < 4; ++t) {
        const int j0 = w * 64 + t * 16;
        const float* yrow = Y + (size_t)(j0 + col) * DD + quad * 8;
        bf16x8 bfrag[4];
        float ny_own = 0.f;
#pragma unroll
        for (int c = 0; c < 4; ++c) {
            const float4 u0 = *(const float4*)(yrow + c * 32);
            const float4 u1 = *(const float4*)(yrow + c * 32 + 4);
            ny_own += u0.x*u0.x + u0.y*u0.y + u0.z*u0.z + u0.w*u0.w;
            ny_own += u1.x*u1.x + u1.y*u1.y + u1.z*u1.z + u1.w*u1.w;
            bf16x8 f;
            f[0]=(__bf16)u0.x; f[1]=(__bf16)u0.y; f[2]=(__bf16)u0.z; f[3]=(__bf16)u0.w;
            f[4]=(__bf16)u1.x; f[5]=(__bf16)u1.y; f[6]=(__bf16)u1.z; f[7]=(__bf16)u1.w;
            bfrag[c] = f;
        }
        ny_own += __shfl_xor(ny_own, 16);
        ny_own += __shfl_xor(ny_own, 32);   // ||y_(j0+col)||^2

        floatx4 acc = {0.f, 0.f, 0.f, 0.f};
#pragma unroll
        for (int c = 0; c < 4; ++c)
            acc = __builtin_amdgcn_mfma_f32_16x16x32_bf16(afrag[c], bfrag[c], acc, 0, 0, 0);

#pragma unroll
        for (int r = 0; r < 4; ++r) {
            const int row = quad * 4 + r;          // C: col=lane&15, row=quad*4+reg
            float d2 = fmaf(-2.f, acc[r], nxr[r] + ny_own);
            d2 = fmaxf(d2, 0.f);
            const float dm = SCALE * sqrtf(d2);
            denom[r] += __expf(dm);
            if (j0 + col == i0 + row) pos[r] = dm;
        }
    }

    // reduce across the 16 cols of each quad group
#pragma unroll
    for (int r = 0; r < 4; ++r) {
#pragma unroll
        for (int m = 1; m < 16; m <<= 1) {
            denom[r] += __shfl_xor(denom[r], m);
            pos[r]   += __shfl_xor(pos[r], m);
        }
    }

    // cross-wave combine: each wave covered a disjoint 64-col j-range
    __shared__ float ld_den[16][16];
    __shared__ float ld_pos[16][16];
    if (col == 0) {
#pragma unroll
        for (int r = 0; r < 4; ++r) {
            ld_den[w][quad * 4 + r] = denom[r];
            ld_pos[w][quad * 4 + r] = pos[r];
        }
    }
    __syncthreads();
    float s = 0.f;
    if (tid < 16) {
        float den = 0.f, po = 0.f;
#pragma unroll
        for (int ww = 0; ww < 16; ++ww) {
            den += ld_den[ww][tid];
            po  += ld_pos[ww][tid];
        }
        s = po - logf(den);              // contribution of row i0+tid
#pragma unroll
        for (int m = 1; m < 16; m <<= 1) s += __shfl_xor(s, m);
    }
    if (tid == 0) {
        const float v = s * (1.0f / (float)NN);
        // clear harness 0xAA poison race-free: each word's first access is a CAS
        unsigned* uo = (unsigned*)out;
        atomicCAS(&uo[0], 0xAAAAAAAAu, 0u);
        atomicCAS(&uo[1], 0xAAAAAAAAu, 0u);
        atomicCAS(&uo[2], 0xAAAAAAAAu, 0u);
        atomicAdd(&out[0], v);          // alignment_loss (beta=1)
        atomicAdd(&out[1 + p], v);      // center (p=0) / instance (p=1)
    }
}

extern "C" void kernel_launch(void* const* d_in, const int* in_sizes, int n_in,
                              void* d_out, int out_size, void* d_ws, size_t ws_size,
                              hipStream_t stream) {
    const float* x   = (const float*)d_in[0];
    const float* aug = (const float*)d_in[1];
    const float* lp  = (const float*)d_in[2];
    float* out       = (float*)d_out;
    align_fused<<<dim3(64, 2), 1024, 0, stream>>>(x, lp, aug, out);
}

// Round 4
// 80.247 us; speedup vs baseline: 1.0240x; 1.0240x over previous
//
#include <hip/hip_runtime.h>
#include <math.h>

// N=1024, D=128, tau=1, beta=1. Single fused kernel + 4-byte memset node.
//   grid (64, 2): blockIdx.x = 16-row i-tile, blockIdx.y = pair (0: x/lp, 1: x/aug)
//   block 1024 threads = 16 waves; wave w covers j in [w*64, w*64+64) as 4 16-col tiles.
//   fp32 loads from d_in -> bf16 frags + exact fp32 norms -> MFMA dots ->
//   d2 = nx+ny-2dot -> dm -> exp-rowsum -> pos - log(denom) -> per-block scalar.
//   Tail: ticket finalize (1 release-store + 1 fetch_add per block; last block
//   reduces 128 partials, writes out). No same-line atomic herd.
#define NN 1024
#define DD 128

typedef __bf16 bf16x8 __attribute__((ext_vector_type(8)));
typedef float  floatx4 __attribute__((ext_vector_type(4)));

__global__ __launch_bounds__(1024) void align_fused(
    const float* __restrict__ x, const float* __restrict__ lp,
    const float* __restrict__ aug, float* __restrict__ out,
    float* __restrict__ ws_f /* [128] partials */, unsigned* __restrict__ counter)
{
    const float SCALE = 0.08838834764831845f;  // 1/sqrt(128)
    const int p    = blockIdx.y;
    const float* __restrict__ Y = p ? aug : lp;
    const int i0   = blockIdx.x * 16;
    const int tid  = threadIdx.x;
    const int w    = tid >> 6;    // wave 0..15
    const int lane = tid & 63;
    const int col  = lane & 15;   // A-frag row / C col
    const int quad = lane >> 4;   // 0..3

    // ---- A fragments (x row i0+col, k = c*32 + quad*8 + [0..7]) + exact norm ----
    const float* xrow = x + (size_t)(i0 + col) * DD + quad * 8;
    bf16x8 afrag[4];
    float nx_own = 0.f;
#pragma unroll
    for (int c = 0; c < 4; ++c) {
        const float4 u0 = *(const float4*)(xrow + c * 32);
        const float4 u1 = *(const float4*)(xrow + c * 32 + 4);
        nx_own += u0.x*u0.x + u0.y*u0.y + u0.z*u0.z + u0.w*u0.w;
        nx_own += u1.x*u1.x + u1.y*u1.y + u1.z*u1.z + u1.w*u1.w;
        bf16x8 f;
        f[0]=(__bf16)u0.x; f[1]=(__bf16)u0.y; f[2]=(__bf16)u0.z; f[3]=(__bf16)u0.w;
        f[4]=(__bf16)u1.x; f[5]=(__bf16)u1.y; f[6]=(__bf16)u1.z; f[7]=(__bf16)u1.w;
        afrag[c] = f;
    }
    nx_own += __shfl_xor(nx_own, 16);
    nx_own += __shfl_xor(nx_own, 32);     // full ||x_(i0+col)||^2
    float nxr[4];
#pragma unroll
    for (int r = 0; r < 4; ++r) nxr[r] = __shfl(nx_own, quad * 4 + r);

    float denom[4] = {0.f, 0.f, 0.f, 0.f};
    float pos[4]   = {0.f, 0.f, 0.f, 0.f};

#pragma unroll
    for (int t = 0; t < 4; ++t) {
        const int j0 = w * 64 + t * 16;
        const float* yrow = Y + (size_t)(j0 + col) * DD + quad * 8;
        bf16x8 bfrag[4];
        float ny_own = 0.f;
#pragma unroll
        for (int c = 0; c < 4; ++c) {
            const float4 u0 = *(const float4*)(yrow + c * 32);
            const float4 u1 = *(const float4*)(yrow + c * 32 + 4);
            ny_own += u0.x*u0.x + u0.y*u0.y + u0.z*u0.z + u0.w*u0.w;
            ny_own += u1.x*u1.x + u1.y*u1.y + u1.z*u1.z + u1.w*u1.w;
            bf16x8 f;
            f[0]=(__bf16)u0.x; f[1]=(__bf16)u0.y; f[2]=(__bf16)u0.z; f[3]=(__bf16)u0.w;
            f[4]=(__bf16)u1.x; f[5]=(__bf16)u1.y; f[6]=(__bf16)u1.z; f[7]=(__bf16)u1.w;
            bfrag[c] = f;
        }
        ny_own += __shfl_xor(ny_own, 16);
        ny_own += __shfl_xor(ny_own, 32);   // ||y_(j0+col)||^2

        floatx4 acc = {0.f, 0.f, 0.f, 0.f};
#pragma unroll
        for (int c = 0; c < 4; ++c)
            acc = __builtin_amdgcn_mfma_f32_16x16x32_bf16(afrag[c], bfrag[c], acc, 0, 0, 0);

#pragma unroll
        for (int r = 0; r < 4; ++r) {
            const int row = quad * 4 + r;          // C: col=lane&15, row=quad*4+reg
            float d2 = fmaf(-2.f, acc[r], nxr[r] + ny_own);
            d2 = fmaxf(d2, 0.f);
            const float dm = SCALE * sqrtf(d2);
            denom[r] += __expf(dm);
            if (j0 + col == i0 + row) pos[r] = dm;
        }
    }

    // reduce across the 16 cols of each quad group
#pragma unroll
    for (int r = 0; r < 4; ++r) {
#pragma unroll
        for (int m = 1; m < 16; m <<= 1) {
            denom[r] += __shfl_xor(denom[r], m);
            pos[r]   += __shfl_xor(pos[r], m);
        }
    }

    // cross-wave combine: each wave covered a disjoint 64-col j-range
    __shared__ float ld_den[16][16];
    __shared__ float ld_pos[16][16];
    __shared__ int s_last;
    if (col == 0) {
#pragma unroll
        for (int r = 0; r < 4; ++r) {
            ld_den[w][quad * 4 + r] = denom[r];
            ld_pos[w][quad * 4 + r] = pos[r];
        }
    }
    __syncthreads();
    float s = 0.f;
    if (tid < 16) {
        float den = 0.f, po = 0.f;
#pragma unroll
        for (int ww = 0; ww < 16; ++ww) {
            den += ld_den[ww][tid];
            po  += ld_pos[ww][tid];
        }
        s = po - logf(den);              // contribution of row i0+tid
#pragma unroll
        for (int m = 1; m < 16; m <<= 1) s += __shfl_xor(s, m);
    }
    // ---- ticket finalize: 1 release-store + 1 counter add per block ----
    if (tid == 0) {
        __hip_atomic_store(&ws_f[p * 64 + blockIdx.x], s,
                           __ATOMIC_RELEASE, __HIP_MEMORY_SCOPE_AGENT);
        const unsigned old = __hip_atomic_fetch_add(counter, 1u,
                           __ATOMIC_ACQ_REL, __HIP_MEMORY_SCOPE_AGENT);
        s_last = (old == 127u) ? 1 : 0;
    }
    __syncthreads();
    if (!s_last) return;

    // last block: reduce the 128 partials (wave 0 = center, wave 1 = instance)
    float v = 0.f;
    if (tid < 128)
        v = __hip_atomic_load(&ws_f[tid], __ATOMIC_RELAXED, __HIP_MEMORY_SCOPE_AGENT);
#pragma unroll
    for (int m = 1; m < 64; m <<= 1) v += __shfl_xor(v, m);
    __shared__ float s_pair[2];
    if (tid == 0)  s_pair[0] = v;
    if (tid == 64) s_pair[1] = v;
    __syncthreads();
    if (tid == 0) {
        const float inv = 1.0f / (float)NN;
        const float c  = s_pair[0] * inv;   // center alignment loss
        const float ia = s_pair[1] * inv;   // instance alignment loss
        out[0] = c + ia;
        out[1] = c;
        out[2] = ia;
    }
}

extern "C" void kernel_launch(void* const* d_in, const int* in_sizes, int n_in,
                              void* d_out, int out_size, void* d_ws, size_t ws_size,
                              hipStream_t stream) {
    const float* x   = (const float*)d_in[0];
    const float* aug = (const float*)d_in[1];
    const float* lp  = (const float*)d_in[2];
    float* out       = (float*)d_out;
    float*    ws_f    = (float*)d_ws;                 // [128] block partials
    unsigned* counter = (unsigned*)((char*)d_ws + 1024);

    hipMemsetAsync(counter, 0, sizeof(unsigned), stream);   // graph-legal memset node
    align_fused<<<dim3(64, 2), 1024, 0, stream>>>(x, lp, aug, out, ws_f, counter);
}

// Round 5
// 72.201 us; speedup vs baseline: 1.1381x; 1.1114x over previous
//
#include <hip/hip_runtime.h>
#include <math.h>

// N=1024, D=128, tau=1, beta=1. Two-node pipeline, no atomics, no memset.
//
// main:  grid (64, 2, 8), block 256 (4 waves).
//   blockIdx.x = 16-row i-tile, .y = pair (0: x/lp, 1: x/aug), .z = 128-col j-chunk.
//   Wave w covers j = jc*128 + t*64 + w*16, t=0..1 (16-col MFMA tiles).
//   fp32 loads straight from d_in -> bf16 frags + exact fp32 norms (shuffle) ->
//   MFMA dots -> d2 = nx+ny-2dot -> dm = sqrt(d2)/sqrt(D) -> exp-rowsum.
//   Writes per-row partial denoms [2][8][1024] and diagonal dm [2][1024] to ws.
//
// fin:   1 block x 256. den = sum_jc partials; contrib = pos - log(den);
//   reduce 1024 rows per pair; writes out[0..2] with plain stores.
#define NN 1024
#define DD 128

typedef __bf16 bf16x8 __attribute__((ext_vector_type(8)));
typedef float  floatx4 __attribute__((ext_vector_type(4)));

__global__ __launch_bounds__(256) void align_main(
    const float* __restrict__ x, const float* __restrict__ lp,
    const float* __restrict__ aug,
    float* __restrict__ denom_part /* [2][8][1024] */,
    float* __restrict__ posbuf     /* [2][1024] */)
{
    const float SCALE = 0.08838834764831845f;  // 1/sqrt(128)
    const int bx = blockIdx.x;
    const int p  = blockIdx.y;
    const int jc = blockIdx.z;
    const float* __restrict__ Y = p ? aug : lp;

    const int i0   = bx * 16;
    const int tid  = threadIdx.x;
    const int w    = tid >> 6;    // wave 0..3
    const int lane = tid & 63;
    const int col  = lane & 15;   // A-frag row / C col
    const int quad = lane >> 4;   // 0..3

    // ---- A fragments (x row i0+col, k = c*32 + quad*8 + [0..7]) + exact norm ----
    const float* xrow = x + (size_t)(i0 + col) * DD + quad * 8;
    bf16x8 afrag[4];
    float nx_own = 0.f;
#pragma unroll
    for (int c = 0; c < 4; ++c) {
        const float4 u0 = *(const float4*)(xrow + c * 32);
        const float4 u1 = *(const float4*)(xrow + c * 32 + 4);
        nx_own += u0.x*u0.x + u0.y*u0.y + u0.z*u0.z + u0.w*u0.w;
        nx_own += u1.x*u1.x + u1.y*u1.y + u1.z*u1.z + u1.w*u1.w;
        bf16x8 f;
        f[0]=(__bf16)u0.x; f[1]=(__bf16)u0.y; f[2]=(__bf16)u0.z; f[3]=(__bf16)u0.w;
        f[4]=(__bf16)u1.x; f[5]=(__bf16)u1.y; f[6]=(__bf16)u1.z; f[7]=(__bf16)u1.w;
        afrag[c] = f;
    }
    nx_own += __shfl_xor(nx_own, 16);
    nx_own += __shfl_xor(nx_own, 32);     // full ||x_(i0+col)||^2
    float nxr[4];
#pragma unroll
    for (int r = 0; r < 4; ++r) nxr[r] = __shfl(nx_own, quad * 4 + r);

    float denom[4] = {0.f, 0.f, 0.f, 0.f};
    float pos[4]   = {0.f, 0.f, 0.f, 0.f};

#pragma unroll
    for (int t = 0; t < 2; ++t) {
        const int j0 = jc * 128 + t * 64 + w * 16;
        const float* yrow = Y + (size_t)(j0 + col) * DD + quad * 8;
        bf16x8 bfrag[4];
        float ny_own = 0.f;
#pragma unroll
        for (int c = 0; c < 4; ++c) {
            const float4 u0 = *(const float4*)(yrow + c * 32);
            const float4 u1 = *(const float4*)(yrow + c * 32 + 4);
            ny_own += u0.x*u0.x + u0.y*u0.y + u0.z*u0.z + u0.w*u0.w;
            ny_own += u1.x*u1.x + u1.y*u1.y + u1.z*u1.z + u1.w*u1.w;
            bf16x8 f;
            f[0]=(__bf16)u0.x; f[1]=(__bf16)u0.y; f[2]=(__bf16)u0.z; f[3]=(__bf16)u0.w;
            f[4]=(__bf16)u1.x; f[5]=(__bf16)u1.y; f[6]=(__bf16)u1.z; f[7]=(__bf16)u1.w;
            bfrag[c] = f;
        }
        ny_own += __shfl_xor(ny_own, 16);
        ny_own += __shfl_xor(ny_own, 32);   // ||y_(j0+col)||^2

        floatx4 acc = {0.f, 0.f, 0.f, 0.f};
#pragma unroll
        for (int c = 0; c < 4; ++c)
            acc = __builtin_amdgcn_mfma_f32_16x16x32_bf16(afrag[c], bfrag[c], acc, 0, 0, 0);

#pragma unroll
        for (int r = 0; r < 4; ++r) {
            const int row = quad * 4 + r;          // C: col=lane&15, row=quad*4+reg
            float d2 = fmaf(-2.f, acc[r], nxr[r] + ny_own);
            d2 = fmaxf(d2, 0.f);
            const float dm = SCALE * sqrtf(d2);
            denom[r] += __expf(dm);
            if (j0 + col == i0 + row) pos[r] = dm;
        }
    }

    // reduce across the 16 cols of each quad group
#pragma unroll
    for (int r = 0; r < 4; ++r) {
#pragma unroll
        for (int m = 1; m < 16; m <<= 1) {
            denom[r] += __shfl_xor(denom[r], m);
            pos[r]   += __shfl_xor(pos[r], m);
        }
    }

    // cross-wave combine (each wave covered a disjoint 16-col pair of tiles)
    __shared__ float ld_den[4][16];
    __shared__ float ld_pos[4][16];
    if (col == 0) {
#pragma unroll
        for (int r = 0; r < 4; ++r) {
            ld_den[w][quad * 4 + r] = denom[r];
            ld_pos[w][quad * 4 + r] = pos[r];
        }
    }
    __syncthreads();
    if (tid < 16) {
        const float den = ld_den[0][tid] + ld_den[1][tid] + ld_den[2][tid] + ld_den[3][tid];
        denom_part[(size_t)(p * 8 + jc) * NN + i0 + tid] = den;
        if (jc == (bx >> 3)) {   // this chunk holds the diagonal for rows i0..i0+15
            const float po = ld_pos[0][tid] + ld_pos[1][tid] + ld_pos[2][tid] + ld_pos[3][tid];
            posbuf[p * NN + i0 + tid] = po;
        }
    }
}

__global__ __launch_bounds__(256) void align_fin(
    const float* __restrict__ denom_part, const float* __restrict__ posbuf,
    float* __restrict__ out)
{
    const int tid  = threadIdx.x;
    const int w    = tid >> 6;
    const int lane = tid & 63;
    float sum0 = 0.f, sum1 = 0.f;
#pragma unroll
    for (int k = 0; k < 4; ++k) {
        const int row = tid + k * 256;
#pragma unroll
        for (int p = 0; p < 2; ++p) {
            float den = 0.f;
#pragma unroll
            for (int jc = 0; jc < 8; ++jc)
                den += denom_part[(size_t)(p * 8 + jc) * NN + row];
            const float c = posbuf[p * NN + row] - __logf(den);
            if (p) sum1 += c; else sum0 += c;
        }
    }
#pragma unroll
    for (int m = 1; m < 64; m <<= 1) {
        sum0 += __shfl_xor(sum0, m);
        sum1 += __shfl_xor(sum1, m);
    }
    __shared__ float s0[4], s1[4];
    if (lane == 0) { s0[w] = sum0; s1[w] = sum1; }
    __syncthreads();
    if (tid == 0) {
        const float inv = 1.0f / (float)NN;
        const float c  = (s0[0] + s0[1] + s0[2] + s0[3]) * inv;  // center loss
        const float ia = (s1[0] + s1[1] + s1[2] + s1[3]) * inv;  // instance loss
        out[0] = c + ia;     // alignment_loss (beta = 1)
        out[1] = c;
        out[2] = ia;
    }
}

extern "C" void kernel_launch(void* const* d_in, const int* in_sizes, int n_in,
                              void* d_out, int out_size, void* d_ws, size_t ws_size,
                              hipStream_t stream) {
    const float* x   = (const float*)d_in[0];
    const float* aug = (const float*)d_in[1];
    const float* lp  = (const float*)d_in[2];
    float* out       = (float*)d_out;

    float* denom_part = (float*)d_ws;                      // [2][8][1024] = 64 KB
    float* posbuf     = (float*)((char*)d_ws + 65536);     // [2][1024]    =  8 KB

    align_main<<<dim3(64, 2, 8), 256, 0, stream>>>(x, lp, aug, denom_part, posbuf);
    align_fin<<<1, 256, 0, stream>>>(denom_part, posbuf, out);
}